// Round 8
// baseline (88.968 us; speedup 1.0000x reference)
//
#include <hip/hip_runtime.h>
#include <math.h>

#define IN_CH 4
#define KSZ 3
#define NUM_KERNELS 2
#define NPOS 9
#define HH 64
#define WW 64
#define BB 16
#define OH 62
#define OW 62
#define NPATCH (BB*OH*OW)   // 61504 = 1922 * 32
#define NU (NPOS*IN_CH)     // 36 gates per kernel index
#define CHST (HH*WW)
#define BLK 64
#define UF4K (NU*4)         // 144 floats per kernel index (SU2: alpha,beta)

// ---------------------------------------------------------------------------
// Precompute alpha=U00, beta=U01 of U = Rz*Ry*Rx per (kernel,pos,qubit).
// (R7-verified; U = [[a,b],[-b*,a*]].)
// ---------------------------------------------------------------------------
__global__ void qk_precompute(const float* __restrict__ w, float* __restrict__ U) {
    int t = blockIdx.x * blockDim.x + threadIdx.x;
    if (t >= NUM_KERNELS * NU) return;
    int k   = t / NU;
    int rem = t % NU;          // pos*IN_CH + q
    const float* wp = w + k * (NU * 3) + rem * 3;
    float hx = 0.5f * wp[0], hy = 0.5f * wp[1], hz = 0.5f * wp[2];
    float cx = cosf(hx), sx = sinf(hx);
    float cy = cosf(hy), sy = sinf(hy);
    float cz = cosf(hz), sz = sinf(hz);
    float m00r =  cy * cx, m00i =  sy * sx;
    float m01r = -sy * cx, m01i = -cy * sx;
    float* o = U + t * 4;
    o[0] = cz * m00r + sz * m00i;  o[1] = cz * m00i - sz * m00r;  // alpha
    o[2] = cz * m01r + sz * m01i;  o[3] = cz * m01i - sz * m01r;  // beta
}

// lane-pair exchange (lanes 2t <-> 2t+1) via DPP quad_perm [1,0,3,2] — pure
// VALU, no LDS pipe. 0xB1 = 1 | (0<<2) | (3<<4) | (2<<6).
__device__ __forceinline__ float pswap(float v) {
    return __int_as_float(__builtin_amdgcn_mov_dpp(__float_as_int(v), 0xB1, 0xF, 0xF, true));
}

// SU(2) gate on local qubit pairs (i, i|MASK) of the 8 local amps.
template<int MASK>
__device__ __forceinline__ void gate_local(float Lr[8], float Li[8],
                                           float far_, float fai,
                                           float fbr, float fbi) {
    #pragma unroll
    for (int i = 0; i < 8; ++i) {
        if (i & MASK) continue;
        const int j = i | MASK;
        float ar = Lr[i], ai = Li[i], br = Lr[j], bi = Li[j];
        Lr[i] =  far_ * ar - fai * ai + fbr * br - fbi * bi;
        Li[i] =  far_ * ai + fai * ar + fbr * bi + fbi * br;
        Lr[j] = -fbr * ar - fbi * ai + far_ * br + fai * bi;
        Li[j] =  fbi * ar - fbr * ai - fai * br + far_ * bi;
    }
}

// ---------------------------------------------------------------------------
// Main kernel: TWO lanes per (patch,kidx) circuit — lane pair (2t,2t+1).
// Lane parity = qubit-0 bit; each lane holds 8 amps L (bits: q1=4,q2=2,q3=1).
// Waves: 3844 (3.75/SIMD) vs 961-1922 before — attacks R6/R7's finding that
// VALUBusy is pinned at 25-36% by occupancy-starved latency exposure.
// ---------------------------------------------------------------------------
__global__ __launch_bounds__(BLK) void qk_main(const float* __restrict__ x,
                                               const float* __restrict__ Uglob,
                                               float* __restrict__ out) {
    __shared__ float sU[UF4K];
    const int kidx = blockIdx.y;
    const int tid  = threadIdx.x;
    for (int t = tid; t < UF4K; t += BLK) sU[t] = Uglob[kidx * UF4K + t];
    __syncthreads();

    const int hi   = tid & 1;                    // qubit-0 bit of this lane
    const float sgnf = hi ? -1.0f : 1.0f;
    const int p   = blockIdx.x * (BLK / 2) + (tid >> 1);   // 1922*32 == NPATCH
    const int b   = p / (OH * OW);
    const int rem = p - b * (OH * OW);
    const int oh  = rem / OW;
    const int ow  = rem - oh * OW;
    const float* xp = x + b * (IN_CH * CHST) + oh * WW + ow;

    float Lr[8], Li[8];
    #pragma unroll
    for (int i = 0; i < 8; ++i) { Lr[i] = 0.25f; Li[i] = 0.0f; }  // H^⊗4|0>

    #pragma unroll
    for (int kh = 0; kh < KSZ; ++kh) {
        #pragma unroll
        for (int kw = 0; kw < KSZ; ++kw) {
            const int pos = kh * KSZ + kw;
            const float* xq = xp + kh * WW + kw;

            // ---------- qubit 0 (distributed across the lane pair) ----------
            {
                float s, c;
                __sincosf(0.5f * xq[0], &s, &c);
                const float* u = &sU[(pos * IN_CH + 0) * 4];
                const float far_ = c * u[0] + s * u[2], fai = c * u[1] + s * u[3];
                const float fbr  = c * u[2] - s * u[0], fbi = c * u[3] - s * u[1];
                // lane A row0 (f00,f01); lane B row1 (conj(f00), -conj(f01))
                const float o0r = far_,        o0i = sgnf * fai;
                const float o1r = sgnf * fbr,  o1i = fbi;
                float orr[8], ori[8];
                #pragma unroll
                for (int i = 0; i < 8; ++i) { orr[i] = pswap(Lr[i]); ori[i] = pswap(Li[i]); }
                #pragma unroll
                for (int i = 0; i < 8; ++i) {
                    float ar = Lr[i], ai = Li[i], br = orr[i], bi = ori[i];
                    Lr[i] = o0r * ar - o0i * ai + o1r * br - o1i * bi;
                    Li[i] = o0r * ai + o0i * ar + o1r * bi + o1i * br;
                }
            }
            // ---------- qubits 1,2,3 (local masks 4,2,1) ----------
            {
                float s, c;
                __sincosf(0.5f * xq[1 * CHST], &s, &c);
                const float* u = &sU[(pos * IN_CH + 1) * 4];
                gate_local<4>(Lr, Li, c * u[0] + s * u[2], c * u[1] + s * u[3],
                                      c * u[2] - s * u[0], c * u[3] - s * u[1]);
            }
            {
                float s, c;
                __sincosf(0.5f * xq[2 * CHST], &s, &c);
                const float* u = &sU[(pos * IN_CH + 2) * 4];
                gate_local<2>(Lr, Li, c * u[0] + s * u[2], c * u[1] + s * u[3],
                                      c * u[2] - s * u[0], c * u[3] - s * u[1]);
            }
            {
                float s, c;
                __sincosf(0.5f * xq[3 * CHST], &s, &c);
                const float* u = &sU[(pos * IN_CH + 3) * 4];
                gate_local<1>(Lr, Li, c * u[0] + s * u[2], c * u[1] + s * u[3],
                                      c * u[2] - s * u[0], c * u[3] - s * u[1]);
            }

            // ---------- CX ring ----------
            // CX(0->1): control = lane bit -> conditional local swap (cndmask)
            #pragma unroll
            for (int i = 0; i < 4; ++i) {
                const int j = i + 4;
                float ar = Lr[i], ai = Li[i], br = Lr[j], bi = Li[j];
                Lr[i] = hi ? br : ar;  Li[i] = hi ? bi : ai;
                Lr[j] = hi ? ar : br;  Li[j] = hi ? ai : bi;
            }
            // CX(1->2): control bit4, target bit2 -> free relabel (copy-prop)
            #pragma unroll
            for (int i = 0; i < 8; ++i) {
                if ((i & 4) && !(i & 2)) {
                    const int j = i | 2;
                    float tr = Lr[i]; Lr[i] = Lr[j]; Lr[j] = tr;
                    float ti = Li[i]; Li[i] = Li[j]; Li[j] = ti;
                }
            }
            // CX(2->3): control bit2, target bit1 -> free relabel
            #pragma unroll
            for (int i = 0; i < 8; ++i) {
                if ((i & 2) && !(i & 1)) {
                    const int j = i | 1;
                    float tr = Lr[i]; Lr[i] = Lr[j]; Lr[j] = tr;
                    float ti = Li[i]; Li[i] = Li[j]; Li[j] = ti;
                }
            }
            // CX(3->0): control bit0 local, target = lane bit -> cross-lane
            // swap of odd-L amps (both lanes take partner's value)
            #pragma unroll
            for (int i = 1; i < 8; i += 2) {
                Lr[i] = pswap(Lr[i]);
                Li[i] = pswap(Li[i]);
            }
        }
    }

    // ---------- probabilities and <Z_q> ----------
    float p2[8];
    #pragma unroll
    for (int i = 0; i < 8; ++i) p2[i] = Lr[i] * Lr[i] + Li[i] * Li[i];

    float e[4];
    {
        float t0 = 0.f, t1 = 0.f, t2 = 0.f, t3 = 0.f;
        #pragma unroll
        for (int i = 0; i < 8; ++i) {
            t0 += p2[i];
            t1 += (i & 4) ? -p2[i] : p2[i];
            t2 += (i & 2) ? -p2[i] : p2[i];
            t3 += (i & 1) ? -p2[i] : p2[i];
        }
        e[0] = sgnf * t0; e[1] = t1; e[2] = t2; e[3] = t3;
    }
    #pragma unroll
    for (int q = 0; q < 4; ++q) e[q] += pswap(e[q]);   // pair-sum: both lanes have totals

    // lane A writes channels q=0,1; lane B writes q=2,3
    float* ob = out + ((size_t)(b * (NUM_KERNELS * IN_CH) + kidx * IN_CH) * OH + oh) * OW + ow;
    const int qb = hi * 2;
    ob[(size_t)(qb + 0) * (OH * OW)] = e[qb + 0];
    ob[(size_t)(qb + 1) * (OH * OW)] = e[qb + 1];
}

extern "C" void kernel_launch(void* const* d_in, const int* in_sizes, int n_in,
                              void* d_out, int out_size, void* d_ws, size_t ws_size,
                              hipStream_t stream) {
    const float* x = (const float*)d_in[0];
    const float* w = (const float*)d_in[1];
    float* out = (float*)d_out;
    float* U   = (float*)d_ws;   // 288 floats of scratch

    hipLaunchKernelGGL(qk_precompute, dim3(1), dim3(128), 0, stream, w, U);
    dim3 grid(NPATCH / (BLK / 2), NUM_KERNELS);   // 1922 x 2 wg, 1 wave each
    hipLaunchKernelGGL(qk_main, grid, dim3(BLK), 0, stream, x, U, out);
}

// Round 9
// 77.350 us; speedup vs baseline: 1.1502x; 1.1502x over previous
//
#include <hip/hip_runtime.h>
#include <math.h>

#define IN_CH 4
#define KSZ 3
#define NUM_KERNELS 2
#define NPOS 9
#define HH 64
#define WW 64
#define BB 16
#define OH 62
#define OW 62
#define NPATCH (BB*OH*OW)   // 61504 = 961 * 64
#define NU (NPOS*IN_CH)     // 36 gates per kernel index
#define CHST (HH*WW)
#define BLK 64
#define NX (BB*IN_CH*HH*WW) // 262144 unique x values
#define UF8 (NU*8)          // 288 floats: [pos][q][kidx0:a,b | kidx1:a,b]

// ---------------------------------------------------------------------------
// Combined precompute (one launch):
//  * all 262144 threads: sc[i] = (cos(x[i]/2), sin(x[i]/2))  — removes every
//    transcendental from the main kernel (R8 finding: hot-loop sincos at
//    ~13-16 SIMD-cyc each was ~50-65% of kernel time; 8.4x redundancy).
//  * threads 0..71: SU(2) gate params U = Rz*Ry*Rx -> (alpha,beta), stored
//    interleaved per (pos,q): floats [a0r,a0i,b0r,b0i, a1r,a1i,b1r,b1i].
// ---------------------------------------------------------------------------
__global__ void qk_pre(const float* __restrict__ x, const float* __restrict__ w,
                       float2* __restrict__ sc, float* __restrict__ U) {
    const int gid = blockIdx.x * 256 + threadIdx.x;
    if (gid < NX) {
        float s, c;
        __sincosf(0.5f * x[gid], &s, &c);
        sc[gid] = make_float2(c, s);
    }
    if (gid < NUM_KERNELS * NU) {
        const int k   = gid / NU;
        const int rem = gid % NU;          // pos*IN_CH + q
        const float* wp = w + k * (NU * 3) + rem * 3;
        float hx = 0.5f * wp[0], hy = 0.5f * wp[1], hz = 0.5f * wp[2];
        float cx = cosf(hx), sx = sinf(hx);
        float cy = cosf(hy), sy = sinf(hy);
        float cz = cosf(hz), sz = sinf(hz);
        float m00r =  cy * cx, m00i =  sy * sx;    // (Ry*Rx)[0][0]
        float m01r = -sy * cx, m01i = -cy * sx;    // (Ry*Rx)[0][1]
        float* o = U + rem * 8 + k * 4;
        o[0] = cz * m00r + sz * m00i;  o[1] = cz * m00i - sz * m00r;  // alpha
        o[2] = cz * m01r + sz * m01i;  o[3] = cz * m01i - sz * m01r;  // beta
    }
}

// SU(2) gate F=[[fa,fb],[-fb*,fa*]] on pairs (i, i|mask); unrolled context ->
// all indices compile-time -> registers only. (R7-verified.)
__device__ __forceinline__ void gate2(float sr[16], float si[16], const int mask,
                                      const float far_, const float fai,
                                      const float fbr, const float fbi) {
    #pragma unroll
    for (int i = 0; i < 16; ++i) {
        if (i & mask) continue;
        const int j = i | mask;
        float ar = sr[i], ai = si[i], br = sr[j], bi = si[j];
        sr[i] =  far_ * ar - fai * ai + fbr * br - fbi * bi;
        si[i] =  far_ * ai + fai * ar + fbr * bi + fbi * br;
        sr[j] = -fbr * ar - fbi * ai + far_ * br + fai * bi;
        si[j] =  fbi * ar - fbr * ai - fai * br + far_ * bi;
    }
}

__device__ __forceinline__ void cx_ring(float sr[16], float si[16]) {
    #pragma unroll
    for (int e = 0; e < 4; ++e) {
        const int cmask = 8 >> e;
        const int tmask = 8 >> ((e + 1) & 3);
        #pragma unroll
        for (int i = 0; i < 16; ++i) {
            if ((i & cmask) && !(i & tmask)) {
                const int j = i | tmask;
                float tr = sr[i]; sr[i] = sr[j]; sr[j] = tr;
                float ti = si[i]; si[i] = si[j]; si[j] = ti;
            }
        }
    }
}

// ---------------------------------------------------------------------------
// Main kernel: one thread per patch, BOTH kidx circuits (R7 structure —
// amortizes every (c,s) load over two gates). Zero transcendentals: gates are
// pure FMA on L1-hot float2 loads + one LDS b128-broadcast pair per (pos,q).
// ---------------------------------------------------------------------------
__global__ __launch_bounds__(BLK) void qk_main(const float2* __restrict__ sc,
                                               const float* __restrict__ Uglob,
                                               float* __restrict__ out) {
    __shared__ float sU[UF8];
    const int tid = threadIdx.x;
    for (int t = tid; t < UF8; t += BLK) sU[t] = Uglob[t];
    __syncthreads();

    const int p   = blockIdx.x * BLK + tid;   // no tail: 961*64 == NPATCH
    const int b   = p / (OH * OW);
    const int rem = p - b * (OH * OW);
    const int oh  = rem / OW;
    const int ow  = rem - oh * OW;
    const float2* xp = sc + (size_t)b * (IN_CH * CHST) + oh * WW + ow;

    float s0r[16], s0i[16], s1r[16], s1i[16];
    #pragma unroll
    for (int i = 0; i < 16; ++i) {
        s0r[i] = 0.25f; s0i[i] = 0.0f;   // H^⊗4 |0>
        s1r[i] = 0.25f; s1i[i] = 0.0f;
    }

    #pragma unroll
    for (int kh = 0; kh < KSZ; ++kh) {
        #pragma unroll
        for (int kw = 0; kw < KSZ; ++kw) {
            const int pos = kh * KSZ + kw;
            #pragma unroll
            for (int q = 0; q < IN_CH; ++q) {
                const float2 cs = xp[q * CHST + kh * WW + kw];
                const float c = cs.x, s = cs.y;
                const int mask = 8 >> q;
                const float* u = &sU[(pos * IN_CH + q) * 8];
                // kidx 0
                gate2(s0r, s0i, mask,
                      c * u[0] + s * u[2], c * u[1] + s * u[3],
                      c * u[2] - s * u[0], c * u[3] - s * u[1]);
                // kidx 1
                gate2(s1r, s1i, mask,
                      c * u[4] + s * u[6], c * u[5] + s * u[7],
                      c * u[6] - s * u[4], c * u[7] - s * u[5]);
            }
            cx_ring(s0r, s0i);   // register renames in unrolled context
            cx_ring(s1r, s1i);
        }
    }

    // ---- probabilities and <Z_q> for both circuits ----
    float p20[16], p21[16];
    #pragma unroll
    for (int i = 0; i < 16; ++i) {
        p20[i] = s0r[i] * s0r[i] + s0i[i] * s0i[i];
        p21[i] = s1r[i] * s1r[i] + s1i[i] * s1i[i];
    }

    float* ob = out + ((size_t)(b * (NUM_KERNELS * IN_CH)) * OH + oh) * OW + ow;
    #pragma unroll
    for (int q = 0; q < IN_CH; ++q) {
        const int mask = 8 >> q;
        float e0 = 0.0f, e1 = 0.0f;
        #pragma unroll
        for (int i = 0; i < 16; ++i) {
            e0 += (i & mask) ? -p20[i] : p20[i];
            e1 += (i & mask) ? -p21[i] : p21[i];
        }
        ob[(size_t)q * (OH * OW)]           = e0;   // kidx 0, channel q
        ob[(size_t)(IN_CH + q) * (OH * OW)] = e1;   // kidx 1, channel 4+q
    }
}

extern "C" void kernel_launch(void* const* d_in, const int* in_sizes, int n_in,
                              void* d_out, int out_size, void* d_ws, size_t ws_size,
                              hipStream_t stream) {
    const float* x = (const float*)d_in[0];
    const float* w = (const float*)d_in[1];
    float* out = (float*)d_out;
    float*  U  = (float*)d_ws;                         // 288 floats
    float2* sc = (float2*)((char*)d_ws + 4096);        // 2 MB sincos table

    hipLaunchKernelGGL(qk_pre, dim3(NX / 256), dim3(256), 0, stream, x, w, sc, U);
    hipLaunchKernelGGL(qk_main, dim3(NPATCH / BLK), dim3(BLK), 0, stream, sc, U, out);
}